// Round 7
// baseline (494.912 us; speedup 1.0000x reference)
//
#include <hip/hip_runtime.h>
#include <math.h>

#define NB   32
#define CCH  64
#define HWD  1024
#define CHW  65536     // C*H*W per sample
#define EPSV 1e-5f
#define REP_A 2        // diagnostic: surface k_attnA in rocprof top-5
#define REP_W 6        // diagnostic: surface k_attnW in rocprof top-5

typedef __attribute__((ext_vector_type(8))) short bf16x8;
typedef __attribute__((ext_vector_type(4))) float f32x4;

__device__ __forceinline__ unsigned f2b(float x) {
    union { float f; unsigned u; } v; v.f = x;
    return (v.u + 0x7fffu + ((v.u >> 16) & 1u)) >> 16;   // RNE bf16 bits
}

// ---------------------------------------------------------------------------
// Kernel 1: partial LN stats. grid (chunk=8, which=3, n=32), block 256.
// ---------------------------------------------------------------------------
__global__ __launch_bounds__(256)
void k_stats(const float* __restrict__ q, const float* __restrict__ k,
             const float* __restrict__ v, float* __restrict__ part)
{
    const int chunk = blockIdx.x, which = blockIdx.y, n = blockIdx.z;
    const float* x = (which == 0) ? q : (which == 1 ? k : v);
    const float4* x4 = (const float4*)(x + (size_t)n * CHW) + chunk * 2048;
    float s = 0.f, ss = 0.f;
#pragma unroll
    for (int i = 0; i < 8; ++i) {
        float4 t = x4[threadIdx.x + i * 256];
        s  += t.x + t.y + t.z + t.w;
        ss += t.x * t.x + t.y * t.y + t.z * t.z + t.w * t.w;
    }
    __shared__ float rs[256], rss[256];
    rs[threadIdx.x] = s; rss[threadIdx.x] = ss;
    __syncthreads();
    for (int off = 128; off > 0; off >>= 1) {
        if (threadIdx.x < off) {
            rs[threadIdx.x]  += rs[threadIdx.x + off];
            rss[threadIdx.x] += rss[threadIdx.x + off];
        }
        __syncthreads();
    }
    if (threadIdx.x == 0) {
        const int b = (n * 3 + which) * 8 + chunk;
        part[b * 2 + 0] = rs[0];
        part[b * 2 + 1] = rss[0];
    }
}

// ---------------------------------------------------------------------------
// Kernel 2: finish stats + LayerNorm + 1x1-conv projections.
// grid (pt=16, n=32), block 256. LDS 35 KB -> 4 blocks/CU.
// ---------------------------------------------------------------------------
__global__ __launch_bounds__(256, 4)
void k_proj(const float* __restrict__ q,  const float* __restrict__ k,  const float* __restrict__ v,
            const float* __restrict__ w1, const float* __restrict__ b1,
            const float* __restrict__ w2, const float* __restrict__ b2,
            const float* __restrict__ w3, const float* __restrict__ b3,
            const float* __restrict__ wq, const float* __restrict__ bq,
            const float* __restrict__ wk, const float* __restrict__ bk,
            const float* __restrict__ wv, const float* __restrict__ bv,
            const float* __restrict__ part,
            float* __restrict__ qn, short* __restrict__ pqt,
            short* __restrict__ pkt, short* __restrict__ pvb)
{
    __shared__ float xn[64][68];
    __shared__ float wt[64][68];
    __shared__ float musd[6];
    const int pt = blockIdx.x, n = blockIdx.y;
    const int t = threadIdx.x;

    if (t < 3) {
        float s = 0.f, ss = 0.f;
#pragma unroll
        for (int cidx = 0; cidx < 8; ++cidx) {
            const int b = (n * 3 + t) * 8 + cidx;
            s  += part[b * 2 + 0];
            ss += part[b * 2 + 1];
        }
        const float mu = s * (1.0f / CHW);
        musd[t * 2 + 0] = mu;
        musd[t * 2 + 1] = rsqrtf(ss * (1.0f / CHW) - mu * mu + EPSV);
    }
    __syncthreads();

    const float* src[3]   = {q, k, v};
    const float* lw[3]    = {w1, w2, w3};
    const float* lb[3]    = {b1, b2, b3};
    const float* pw[3]    = {wq, wk, wv};
    const float* pbias[3] = {bq, bk, bv};
    const int p   = t & 63;
    const int ob  = (t >> 6) * 16;
    const int pix = pt * 64 + p;

    for (int tt = 0; tt < 3; ++tt) {
        for (int idx = t; idx < 4096; idx += 256) {
            const int o = idx >> 6, c = idx & 63;
            wt[c][o] = pw[tt][idx];
        }
        const float mu = musd[tt * 2], is = musd[tt * 2 + 1];
        for (int idx = t; idx < 1024; idx += 256) {
            const int c = idx >> 4, p4 = idx & 15;
            const int gi = c * HWD + pt * 64 + p4 * 4;
            float4 xv = *(const float4*)&src[tt][(size_t)n * CHW + gi];
            float4 w4 = *(const float4*)&lw[tt][gi];
            float4 b4 = *(const float4*)&lb[tt][gi];
            float4 r;
            r.x = (xv.x - mu) * is * w4.x + b4.x;
            r.y = (xv.y - mu) * is * w4.y + b4.y;
            r.z = (xv.z - mu) * is * w4.z + b4.z;
            r.w = (xv.w - mu) * is * w4.w + b4.w;
            *(float4*)&xn[c][p4 * 4] = r;
            if (tt == 0) *(float4*)&qn[(size_t)n * CHW + gi] = r;
        }
        __syncthreads();

        float acc[16];
#pragma unroll
        for (int i = 0; i < 16; ++i) acc[i] = pbias[tt][ob + i];
#pragma unroll 4
        for (int c = 0; c < 64; ++c) {
            const float xv = xn[c][p];
#pragma unroll
            for (int o4 = 0; o4 < 4; ++o4) {
                float4 w4 = *(const float4*)&wt[c][ob + o4 * 4];
                acc[o4 * 4 + 0] += w4.x * xv;
                acc[o4 * 4 + 1] += w4.y * xv;
                acc[o4 * 4 + 2] += w4.z * xv;
                acc[o4 * 4 + 3] += w4.w * xv;
            }
        }
        if (tt == 2) {          // V: [c][pix] bf16
#pragma unroll
            for (int i = 0; i < 16; ++i)
                pvb[(size_t)n * CHW + (ob + i) * HWD + pix] = (short)f2b(acc[i]);
        } else {                // Q^T / K^T: [pix][c] bf16 (Q pre-scaled 1/8)
            const float sc = (tt == 0) ? 0.125f : 1.0f;
            unsigned u[8];
#pragma unroll
            for (int i = 0; i < 8; ++i)
                u[i] = (f2b(acc[2 * i + 1] * sc) << 16) | f2b(acc[2 * i] * sc);
            short* dst = (tt == 0) ? pqt : pkt;
            *(uint4*)&dst[(size_t)n * CHW + pix * 64 + ob]     = *(uint4*)&u[0];
            *(uint4*)&dst[(size_t)n * CHW + pix * 64 + ob + 8] = *(uint4*)&u[4];
        }
        __syncthreads();
    }
}

// ---------------------------------------------------------------------------
// Kernel 3a (MFMA): S + softmax stats + PV + residual. NO attn write.
// DIAGNOSTIC: whole body repeated REP_A times (idempotent — identical writes)
// so its dispatch duration exceeds the harness fills and surfaces in top-5
// rocprof rows with full counters.
// ---------------------------------------------------------------------------
__global__ __launch_bounds__(512, 4)
void k_attnA(const short* __restrict__ pqt, const short* __restrict__ pkt,
             const short* __restrict__ pvb, const float* __restrict__ qn,
             float* __restrict__ xout,
             float* __restrict__ colmax, float* __restrict__ colinv)
{
    __shared__ __align__(16) char smem[65536 + 4608 + 2048];
    short* q_lds = (short*)(smem + 65536);
    float* wredA = (float*)(smem + 65536 + 4608);
    float* wredB = wredA + 256;

    const int wg  = blockIdx.x;
    const int xcd = wg & 7, lid = wg >> 3;
    const int n   = xcd * 4 + (lid >> 5);
    const int jb  = lid & 31;
    const size_t nb = (size_t)n * CHW;
    const int t = threadIdx.x;
    const int w = t >> 6;
    const int l = t & 63;
    const int l15 = l & 15, lg = l >> 4;
    const int ibase = w * 128;

#pragma unroll 1
    for (int rep = 0; rep < REP_A; ++rep) {
        asm volatile("" ::: "memory");     // no cross-rep CSE/hoist
        __syncthreads();                   // protect LDS reuse across reps

        if (t < 256) {
            const int j = t >> 3, c8 = (t & 7) * 8;
            *(bf16x8*)&q_lds[j * 72 + c8] =
                *(const bf16x8*)&pqt[nb + (size_t)(jb * 32 + j) * 64 + c8];
        }
        __syncthreads();

        // ---- phase 1: S = K^T Q
        f32x4 acc[8][2] = {};
#pragma unroll
        for (int ks = 0; ks < 2; ++ks) {
            bf16x8 bqf[2];
#pragma unroll
            for (int jt = 0; jt < 2; ++jt)
                bqf[jt] = *(const bf16x8*)&q_lds[(jt * 16 + l15) * 72 + ks * 32 + lg * 8];
#pragma unroll
            for (int f = 0; f < 8; ++f) {
                const int i = ibase + f * 16 + l15;
                bf16x8 af = *(const bf16x8*)&pkt[nb + (size_t)i * 64 + ks * 32 + lg * 8];
#pragma unroll
                for (int jt = 0; jt < 2; ++jt)
                    acc[f][jt] = __builtin_amdgcn_mfma_f32_16x16x32_bf16(
                        af, bqf[jt], acc[f][jt], 0, 0, 0);
            }
        }

        // ---- phase 2: column softmax reductions
        {
            float mx[2];
#pragma unroll
            for (int jt = 0; jt < 2; ++jt) {
                float m = -1e30f;
#pragma unroll
                for (int f = 0; f < 8; ++f)
#pragma unroll
                    for (int r = 0; r < 4; ++r) m = fmaxf(m, acc[f][jt][r]);
                m = fmaxf(m, __shfl_xor(m, 16));
                m = fmaxf(m, __shfl_xor(m, 32));
                mx[jt] = m;
            }
            if (l < 16) {
#pragma unroll
                for (int jt = 0; jt < 2; ++jt) wredA[w * 32 + jt * 16 + l] = mx[jt];
            }
        }
        __syncthreads();

        float sm[2];
#pragma unroll
        for (int jt = 0; jt < 2; ++jt) {
            const int j = jt * 16 + l15;
            float cm = wredA[j];
#pragma unroll
            for (int ww = 1; ww < 8; ++ww) cm = fmaxf(cm, wredA[ww * 32 + j]);
            float s = 0.f;
#pragma unroll
            for (int f = 0; f < 8; ++f)
#pragma unroll
                for (int r = 0; r < 4; ++r) {
                    float e = __expf(acc[f][jt][r] - cm);
                    acc[f][jt][r] = e;
                    s += e;
                }
            s += __shfl_xor(s, 16);
            s += __shfl_xor(s, 32);
            sm[jt] = s;
        }
        if (l < 16) {
#pragma unroll
            for (int jt = 0; jt < 2; ++jt) wredB[w * 32 + jt * 16 + l] = sm[jt];
        }
        __syncthreads();

        // ---- phase 3: normalize; P (bf16) -> LDS (swizzled); col stats
#pragma unroll
        for (int jt = 0; jt < 2; ++jt) {
            const int j = jt * 16 + l15;
            float cm = wredA[j];
            float s  = wredB[j];
#pragma unroll
            for (int ww = 1; ww < 8; ++ww) {
                cm = fmaxf(cm, wredA[ww * 32 + j]);
                s += wredB[ww * 32 + j];
            }
            const float inv = 1.0f / s;
            if (w == 0 && lg == 0) {
                colmax[(size_t)n * HWD + jb * 32 + j] = cm;
                colinv[(size_t)n * HWD + jb * 32 + j] = inv;
            }
#pragma unroll
            for (int f = 0; f < 8; ++f) {
                const int i0 = ibase + f * 16 + lg * 4;
                uint2 pw;
                pw.x = (f2b(acc[f][jt][1] * inv) << 16) | f2b(acc[f][jt][0] * inv);
                pw.y = (f2b(acc[f][jt][3] * inv) << 16) | f2b(acc[f][jt][2] * inv);
                const unsigned byte = (unsigned)j * 2048u + (((unsigned)i0 * 2u) ^ (((unsigned)j & 7u) << 4));
                *(uint2*)(smem + byte) = pw;
            }
        }
        __syncthreads();

        // ---- phase 4: out = V * P
        f32x4 oacc = {};
        const int cm4 = w & 3, jn = w >> 2;
        const int j = jn * 16 + l15;
        __builtin_amdgcn_s_setprio(1);
#pragma unroll 4
        for (int ks = 0; ks < 32; ++ks) {
            bf16x8 av = *(const bf16x8*)&pvb[nb + (size_t)(cm4 * 16 + l15) * HWD + ks * 32 + lg * 8];
            const unsigned ib = (unsigned)(ks * 32 + lg * 8) * 2u;
            bf16x8 bp = *(const bf16x8*)(smem + (unsigned)j * 2048u + (ib ^ (((unsigned)j & 7u) << 4)));
            oacc = __builtin_amdgcn_mfma_f32_16x16x32_bf16(av, bp, oacc, 0, 0, 0);
        }
        __builtin_amdgcn_s_setprio(0);

        // ---- epilogue: x = qn + out
#pragma unroll
        for (int r = 0; r < 4; ++r) {
            const int c = cm4 * 16 + lg * 4 + r;
            const size_t o = nb + (size_t)c * HWD + jb * 32 + j;
            xout[o] = oacc[r] + qn[o];
        }
    }
}

// ---------------------------------------------------------------------------
// Kernel 3b: attn writer. Block owns (n, 64 ROWS i) — page-dense writes.
// DIAGNOSTIC: body repeated REP_W times (idempotent), same rationale.
// ---------------------------------------------------------------------------
__global__ __launch_bounds__(256, 4)
void k_attnW(const short* __restrict__ pqt, const short* __restrict__ pkt,
             const float* __restrict__ colmax, const float* __restrict__ colinv,
             float* __restrict__ attn)
{
    const int wg  = blockIdx.x;
    const int xcd = wg & 7, lid = wg >> 3;       // 512 wgs = 8 XCDs x 64
    const int n   = xcd * 4 + (lid >> 4);
    const int it  = lid & 15;
    const size_t nb = (size_t)n * CHW;
    const int t = threadIdx.x;
    const int w = t >> 6, l = t & 63;
    const int l15 = l & 15, lg = l >> 4;
    const int i0 = it * 64 + w * 16;

    const float* cmp = colmax + (size_t)n * HWD;
    const float* cip = colinv + (size_t)n * HWD;
    float* aout = attn + (size_t)n * HWD * HWD;

#pragma unroll 1
    for (int rep = 0; rep < REP_W; ++rep) {
        asm volatile("" ::: "memory");     // no cross-rep CSE/hoist

        bf16x8 af0 = *(const bf16x8*)&pkt[nb + (size_t)(i0 + l15) * 64 + lg * 8];
        bf16x8 af1 = *(const bf16x8*)&pkt[nb + (size_t)(i0 + l15) * 64 + 32 + lg * 8];

#pragma unroll 2
        for (int js = 0; js < 64; ++js) {
            const int j = js * 16 + l15;
            bf16x8 b0 = *(const bf16x8*)&pqt[nb + (size_t)j * 64 + lg * 8];
            bf16x8 b1 = *(const bf16x8*)&pqt[nb + (size_t)j * 64 + 32 + lg * 8];
            f32x4 a = {};
            a = __builtin_amdgcn_mfma_f32_16x16x32_bf16(af0, b0, a, 0, 0, 0);
            a = __builtin_amdgcn_mfma_f32_16x16x32_bf16(af1, b1, a, 0, 0, 0);
            const float cm  = cmp[j];
            const float inv = cip[j];
#pragma unroll
            for (int r = 0; r < 4; ++r) {
                const int i = i0 + lg * 4 + r;
                aout[(size_t)i * HWD + j] = __expf(a[r] - cm) * inv;
            }
        }
    }
}

// ---------------------------------------------------------------------------
extern "C" void kernel_launch(void* const* d_in, const int* in_sizes, int n_in,
                              void* d_out, int out_size, void* d_ws, size_t ws_size,
                              hipStream_t stream)
{
    const float* q  = (const float*)d_in[0];
    const float* k  = (const float*)d_in[1];
    const float* v  = (const float*)d_in[2];
    const float* w1 = (const float*)d_in[3];
    const float* b1 = (const float*)d_in[4];
    const float* w2 = (const float*)d_in[5];
    const float* b2 = (const float*)d_in[6];
    const float* w3 = (const float*)d_in[7];
    const float* b3 = (const float*)d_in[8];
    const float* wq = (const float*)d_in[9];
    const float* bq = (const float*)d_in[10];
    const float* wk = (const float*)d_in[11];
    const float* bk = (const float*)d_in[12];
    const float* wv = (const float*)d_in[13];
    const float* bv = (const float*)d_in[14];

    // ws layout: part[1536] @0; qn fp32 @4096; pqt/pkt/pvb bf16; colmax/colinv.
    float* ws     = (float*)d_ws;
    float* part   = ws;
    float* qn     = ws + 4096;
    short* pqt    = (short*)(qn + 2097152);
    short* pkt    = pqt + 2097152;
    short* pvb    = pkt + 2097152;
    float* colmax = (float*)(pvb + 2097152);
    float* colinv = colmax + 32768;

    float* xout = (float*)d_out;            // (N, C*H*W)
    float* attn = xout + 2097152;           // (N, HW, HW)

    k_stats<<<dim3(8, 3, 32), 256, 0, stream>>>(q, k, v, part);
    k_proj<<<dim3(16, 32), 256, 0, stream>>>(q, k, v, w1, b1, w2, b2, w3, b3,
                                             wq, bq, wk, bk, wv, bv,
                                             part, qn, pqt, pkt, pvb);
    k_attnA<<<dim3(1024), dim3(512), 0, stream>>>(pqt, pkt, pvb, qn, xout,
                                                  colmax, colinv);
    k_attnW<<<dim3(512), dim3(256), 0, stream>>>(pqt, pkt, colmax, colinv, attn);
}

// Round 8
// 296.848 us; speedup vs baseline: 1.6672x; 1.6672x over previous
//
#include <hip/hip_runtime.h>
#include <math.h>

#define NB   32
#define CCH  64
#define HWD  1024
#define CHW  65536     // C*H*W per sample
#define EPSV 1e-5f
#define REP_A 3        // diagnostic: surface k_attnA in rocprof top-5

typedef __attribute__((ext_vector_type(8))) short bf16x8;
typedef __attribute__((ext_vector_type(4))) float f32x4;

__device__ __forceinline__ unsigned f2b(float x) {
    union { float f; unsigned u; } v; v.f = x;
    return (v.u + 0x7fffu + ((v.u >> 16) & 1u)) >> 16;   // RNE bf16 bits
}

// ---------------------------------------------------------------------------
// Kernel 1: partial LN stats. grid (chunk=8, which=3, n=32), block 256.
// ---------------------------------------------------------------------------
__global__ __launch_bounds__(256)
void k_stats(const float* __restrict__ q, const float* __restrict__ k,
             const float* __restrict__ v, float* __restrict__ part)
{
    const int chunk = blockIdx.x, which = blockIdx.y, n = blockIdx.z;
    const float* x = (which == 0) ? q : (which == 1 ? k : v);
    const float4* x4 = (const float4*)(x + (size_t)n * CHW) + chunk * 2048;
    float s = 0.f, ss = 0.f;
#pragma unroll
    for (int i = 0; i < 8; ++i) {
        float4 t = x4[threadIdx.x + i * 256];
        s  += t.x + t.y + t.z + t.w;
        ss += t.x * t.x + t.y * t.y + t.z * t.z + t.w * t.w;
    }
    __shared__ float rs[256], rss[256];
    rs[threadIdx.x] = s; rss[threadIdx.x] = ss;
    __syncthreads();
    for (int off = 128; off > 0; off >>= 1) {
        if (threadIdx.x < off) {
            rs[threadIdx.x]  += rs[threadIdx.x + off];
            rss[threadIdx.x] += rss[threadIdx.x + off];
        }
        __syncthreads();
    }
    if (threadIdx.x == 0) {
        const int b = (n * 3 + which) * 8 + chunk;
        part[b * 2 + 0] = rs[0];
        part[b * 2 + 1] = rss[0];
    }
}

// ---------------------------------------------------------------------------
// Kernel 2: finish stats + LayerNorm + 1x1-conv projections.
// grid (pt=16, n=32), block 256. LDS 35 KB -> 4 blocks/CU.
// ---------------------------------------------------------------------------
__global__ __launch_bounds__(256, 4)
void k_proj(const float* __restrict__ q,  const float* __restrict__ k,  const float* __restrict__ v,
            const float* __restrict__ w1, const float* __restrict__ b1,
            const float* __restrict__ w2, const float* __restrict__ b2,
            const float* __restrict__ w3, const float* __restrict__ b3,
            const float* __restrict__ wq, const float* __restrict__ bq,
            const float* __restrict__ wk, const float* __restrict__ bk,
            const float* __restrict__ wv, const float* __restrict__ bv,
            const float* __restrict__ part,
            float* __restrict__ qn, short* __restrict__ pqt,
            short* __restrict__ pkt, short* __restrict__ pvb)
{
    __shared__ float xn[64][68];
    __shared__ float wt[64][68];
    __shared__ float musd[6];
    const int pt = blockIdx.x, n = blockIdx.y;
    const int t = threadIdx.x;

    if (t < 3) {
        float s = 0.f, ss = 0.f;
#pragma unroll
        for (int cidx = 0; cidx < 8; ++cidx) {
            const int b = (n * 3 + t) * 8 + cidx;
            s  += part[b * 2 + 0];
            ss += part[b * 2 + 1];
        }
        const float mu = s * (1.0f / CHW);
        musd[t * 2 + 0] = mu;
        musd[t * 2 + 1] = rsqrtf(ss * (1.0f / CHW) - mu * mu + EPSV);
    }
    __syncthreads();

    const float* src[3]   = {q, k, v};
    const float* lw[3]    = {w1, w2, w3};
    const float* lb[3]    = {b1, b2, b3};
    const float* pw[3]    = {wq, wk, wv};
    const float* pbias[3] = {bq, bk, bv};
    const int p   = t & 63;
    const int ob  = (t >> 6) * 16;
    const int pix = pt * 64 + p;

    for (int tt = 0; tt < 3; ++tt) {
        for (int idx = t; idx < 4096; idx += 256) {
            const int o = idx >> 6, c = idx & 63;
            wt[c][o] = pw[tt][idx];
        }
        const float mu = musd[tt * 2], is = musd[tt * 2 + 1];
        for (int idx = t; idx < 1024; idx += 256) {
            const int c = idx >> 4, p4 = idx & 15;
            const int gi = c * HWD + pt * 64 + p4 * 4;
            float4 xv = *(const float4*)&src[tt][(size_t)n * CHW + gi];
            float4 w4 = *(const float4*)&lw[tt][gi];
            float4 b4 = *(const float4*)&lb[tt][gi];
            float4 r;
            r.x = (xv.x - mu) * is * w4.x + b4.x;
            r.y = (xv.y - mu) * is * w4.y + b4.y;
            r.z = (xv.z - mu) * is * w4.z + b4.z;
            r.w = (xv.w - mu) * is * w4.w + b4.w;
            *(float4*)&xn[c][p4 * 4] = r;
            if (tt == 0) *(float4*)&qn[(size_t)n * CHW + gi] = r;
        }
        __syncthreads();

        float acc[16];
#pragma unroll
        for (int i = 0; i < 16; ++i) acc[i] = pbias[tt][ob + i];
#pragma unroll 4
        for (int c = 0; c < 64; ++c) {
            const float xv = xn[c][p];
#pragma unroll
            for (int o4 = 0; o4 < 4; ++o4) {
                float4 w4 = *(const float4*)&wt[c][ob + o4 * 4];
                acc[o4 * 4 + 0] += w4.x * xv;
                acc[o4 * 4 + 1] += w4.y * xv;
                acc[o4 * 4 + 2] += w4.z * xv;
                acc[o4 * 4 + 3] += w4.w * xv;
            }
        }
        if (tt == 2) {          // V: [c][pix] bf16
#pragma unroll
            for (int i = 0; i < 16; ++i)
                pvb[(size_t)n * CHW + (ob + i) * HWD + pix] = (short)f2b(acc[i]);
        } else {                // Q^T / K^T: [pix][c] bf16 (Q pre-scaled 1/8)
            const float sc = (tt == 0) ? 0.125f : 1.0f;
            unsigned u[8];
#pragma unroll
            for (int i = 0; i < 8; ++i)
                u[i] = (f2b(acc[2 * i + 1] * sc) << 16) | f2b(acc[2 * i] * sc);
            short* dst = (tt == 0) ? pqt : pkt;
            *(uint4*)&dst[(size_t)n * CHW + pix * 64 + ob]     = *(uint4*)&u[0];
            *(uint4*)&dst[(size_t)n * CHW + pix * 64 + ob + 8] = *(uint4*)&u[4];
        }
        __syncthreads();
    }
}

// ---------------------------------------------------------------------------
// Kernel 3a (MFMA): S + softmax stats + PV + residual. NO attn write.
// DIAGNOSTIC: body repeated REP_A times (idempotent) to surface counters.
// ---------------------------------------------------------------------------
__global__ __launch_bounds__(512, 4)
void k_attnA(const short* __restrict__ pqt, const short* __restrict__ pkt,
             const short* __restrict__ pvb, const float* __restrict__ qn,
             float* __restrict__ xout,
             float* __restrict__ colmax, float* __restrict__ colinv)
{
    __shared__ __align__(16) char smem[65536 + 4608 + 2048];
    short* q_lds = (short*)(smem + 65536);
    float* wredA = (float*)(smem + 65536 + 4608);
    float* wredB = wredA + 256;

    const int wg  = blockIdx.x;
    const int xcd = wg & 7, lid = wg >> 3;
    const int n   = xcd * 4 + (lid >> 5);
    const int jb  = lid & 31;
    const size_t nb = (size_t)n * CHW;
    const int t = threadIdx.x;
    const int w = t >> 6;
    const int l = t & 63;
    const int l15 = l & 15, lg = l >> 4;
    const int ibase = w * 128;

#pragma unroll 1
    for (int rep = 0; rep < REP_A; ++rep) {
        asm volatile("" ::: "memory");     // no cross-rep CSE/hoist
        __syncthreads();                   // protect LDS reuse across reps

        if (t < 256) {
            const int j = t >> 3, c8 = (t & 7) * 8;
            *(bf16x8*)&q_lds[j * 72 + c8] =
                *(const bf16x8*)&pqt[nb + (size_t)(jb * 32 + j) * 64 + c8];
        }
        __syncthreads();

        // ---- phase 1: S = K^T Q
        f32x4 acc[8][2] = {};
#pragma unroll
        for (int ks = 0; ks < 2; ++ks) {
            bf16x8 bqf[2];
#pragma unroll
            for (int jt = 0; jt < 2; ++jt)
                bqf[jt] = *(const bf16x8*)&q_lds[(jt * 16 + l15) * 72 + ks * 32 + lg * 8];
#pragma unroll
            for (int f = 0; f < 8; ++f) {
                const int i = ibase + f * 16 + l15;
                bf16x8 af = *(const bf16x8*)&pkt[nb + (size_t)i * 64 + ks * 32 + lg * 8];
#pragma unroll
                for (int jt = 0; jt < 2; ++jt)
                    acc[f][jt] = __builtin_amdgcn_mfma_f32_16x16x32_bf16(
                        af, bqf[jt], acc[f][jt], 0, 0, 0);
            }
        }

        // ---- phase 2: column softmax reductions
        {
            float mx[2];
#pragma unroll
            for (int jt = 0; jt < 2; ++jt) {
                float m = -1e30f;
#pragma unroll
                for (int f = 0; f < 8; ++f)
#pragma unroll
                    for (int r = 0; r < 4; ++r) m = fmaxf(m, acc[f][jt][r]);
                m = fmaxf(m, __shfl_xor(m, 16));
                m = fmaxf(m, __shfl_xor(m, 32));
                mx[jt] = m;
            }
            if (l < 16) {
#pragma unroll
                for (int jt = 0; jt < 2; ++jt) wredA[w * 32 + jt * 16 + l] = mx[jt];
            }
        }
        __syncthreads();

        float sm[2];
#pragma unroll
        for (int jt = 0; jt < 2; ++jt) {
            const int j = jt * 16 + l15;
            float cm = wredA[j];
#pragma unroll
            for (int ww = 1; ww < 8; ++ww) cm = fmaxf(cm, wredA[ww * 32 + j]);
            float s = 0.f;
#pragma unroll
            for (int f = 0; f < 8; ++f)
#pragma unroll
                for (int r = 0; r < 4; ++r) {
                    float e = __expf(acc[f][jt][r] - cm);
                    acc[f][jt][r] = e;
                    s += e;
                }
            s += __shfl_xor(s, 16);
            s += __shfl_xor(s, 32);
            sm[jt] = s;
        }
        if (l < 16) {
#pragma unroll
            for (int jt = 0; jt < 2; ++jt) wredB[w * 32 + jt * 16 + l] = sm[jt];
        }
        __syncthreads();

        // ---- phase 3: normalize; P (bf16) -> LDS (swizzled); col stats
#pragma unroll
        for (int jt = 0; jt < 2; ++jt) {
            const int j = jt * 16 + l15;
            float cm = wredA[j];
            float s  = wredB[j];
#pragma unroll
            for (int ww = 1; ww < 8; ++ww) {
                cm = fmaxf(cm, wredA[ww * 32 + j]);
                s += wredB[ww * 32 + j];
            }
            const float inv = 1.0f / s;
            if (w == 0 && lg == 0) {
                colmax[(size_t)n * HWD + jb * 32 + j] = cm;
                colinv[(size_t)n * HWD + jb * 32 + j] = inv;
            }
#pragma unroll
            for (int f = 0; f < 8; ++f) {
                const int i0 = ibase + f * 16 + lg * 4;
                uint2 pw;
                pw.x = (f2b(acc[f][jt][1] * inv) << 16) | f2b(acc[f][jt][0] * inv);
                pw.y = (f2b(acc[f][jt][3] * inv) << 16) | f2b(acc[f][jt][2] * inv);
                const unsigned byte = (unsigned)j * 2048u + (((unsigned)i0 * 2u) ^ (((unsigned)j & 7u) << 4));
                *(uint2*)(smem + byte) = pw;
            }
        }
        __syncthreads();

        // ---- phase 4: out = V * P
        f32x4 oacc = {};
        const int cm4 = w & 3, jn = w >> 2;
        const int j = jn * 16 + l15;
        __builtin_amdgcn_s_setprio(1);
#pragma unroll 4
        for (int ks = 0; ks < 32; ++ks) {
            bf16x8 av = *(const bf16x8*)&pvb[nb + (size_t)(cm4 * 16 + l15) * HWD + ks * 32 + lg * 8];
            const unsigned ib = (unsigned)(ks * 32 + lg * 8) * 2u;
            bf16x8 bp = *(const bf16x8*)(smem + (unsigned)j * 2048u + (ib ^ (((unsigned)j & 7u) << 4)));
            oacc = __builtin_amdgcn_mfma_f32_16x16x32_bf16(av, bp, oacc, 0, 0, 0);
        }
        __builtin_amdgcn_s_setprio(0);

        // ---- epilogue: x = qn + out
#pragma unroll
        for (int r = 0; r < 4; ++r) {
            const int c = cm4 * 16 + lg * 4 + r;
            const size_t o = nb + (size_t)c * HWD + jb * 32 + j;
            xout[o] = oacc[r] + qn[o];
        }
    }
}

// ---------------------------------------------------------------------------
// Kernel 3b v2: attn writer, SWAPPED MFMA operands (A=Q-frag, B=K-frag) so
// D[row=j][col=i]: lane holds 4 CONSECUTIVE j at one i -> dwordx4 stores
// (16 B/lane, 4x fewer store instrs than v1's scalar dword scatter).
// Grid 2048 (= 8 blocks/CU -> 32 waves/CU, was 8): fixes v1's measured
// latency-bound profile (2.6 TB/s, 24% occupancy, VALU 11%).
// Block = (n, igrp, jq): wave w -> rows i0 = igrp*64 + w*16, j in jq*256+...
// ---------------------------------------------------------------------------
__global__ __launch_bounds__(256, 8)
void k_attnW(const short* __restrict__ pqt, const short* __restrict__ pkt,
             const float* __restrict__ colmax, const float* __restrict__ colinv,
             float* __restrict__ attn)
{
    const int wg  = blockIdx.x;
    const int xcd = wg & 7, lid = wg >> 3;       // 2048 wgs = 8 XCDs x 256
    const int n   = xcd * 4 + (lid >> 6);
    const int sub = lid & 63;
    const int igrp = sub >> 2, jq = sub & 3;
    const size_t nb = (size_t)n * CHW;
    const int t = threadIdx.x;
    const int w = t >> 6, l = t & 63;
    const int l15 = l & 15, lg = l >> 4;
    const int i0 = igrp * 64 + w * 16;

    // K fragments (B-operand) for this wave's 16 i-rows, register-resident
    const bf16x8 bk0 = *(const bf16x8*)&pkt[nb + (size_t)(i0 + l15) * 64 + lg * 8];
    const bf16x8 bk1 = *(const bf16x8*)&pkt[nb + (size_t)(i0 + l15) * 64 + 32 + lg * 8];

    const float* cmp = colmax + (size_t)n * HWD;
    const float* cip = colinv + (size_t)n * HWD;
    float* aout = attn + (size_t)n * HWD * HWD;

#pragma unroll 2
    for (int js = 0; js < 16; ++js) {
        const int j0 = jq * 256 + js * 16;
        bf16x8 aq0 = *(const bf16x8*)&pqt[nb + (size_t)(j0 + l15) * 64 + lg * 8];
        bf16x8 aq1 = *(const bf16x8*)&pqt[nb + (size_t)(j0 + l15) * 64 + 32 + lg * 8];
        f32x4 a = {};
        a = __builtin_amdgcn_mfma_f32_16x16x32_bf16(aq0, bk0, a, 0, 0, 0);
        a = __builtin_amdgcn_mfma_f32_16x16x32_bf16(aq1, bk1, a, 0, 0, 0);
        // lane: i = i0 + l15 (col), j = j0 + lg*4 + r (row, consecutive)
        const int jv = j0 + lg * 4;
        const float4 cm4 = *(const float4*)&cmp[jv];
        const float4 ci4 = *(const float4*)&cip[jv];
        float4 o;
        o.x = __expf(a[0] - cm4.x) * ci4.x;
        o.y = __expf(a[1] - cm4.y) * ci4.y;
        o.z = __expf(a[2] - cm4.z) * ci4.z;
        o.w = __expf(a[3] - cm4.w) * ci4.w;
        *(float4*)&aout[(size_t)(i0 + l15) * HWD + jv] = o;
    }
}

// ---------------------------------------------------------------------------
extern "C" void kernel_launch(void* const* d_in, const int* in_sizes, int n_in,
                              void* d_out, int out_size, void* d_ws, size_t ws_size,
                              hipStream_t stream)
{
    const float* q  = (const float*)d_in[0];
    const float* k  = (const float*)d_in[1];
    const float* v  = (const float*)d_in[2];
    const float* w1 = (const float*)d_in[3];
    const float* b1 = (const float*)d_in[4];
    const float* w2 = (const float*)d_in[5];
    const float* b2 = (const float*)d_in[6];
    const float* w3 = (const float*)d_in[7];
    const float* b3 = (const float*)d_in[8];
    const float* wq = (const float*)d_in[9];
    const float* bq = (const float*)d_in[10];
    const float* wk = (const float*)d_in[11];
    const float* bk = (const float*)d_in[12];
    const float* wv = (const float*)d_in[13];
    const float* bv = (const float*)d_in[14];

    // ws layout: part[1536] @0; qn fp32 @4096; pqt/pkt/pvb bf16; colmax/colinv.
    float* ws     = (float*)d_ws;
    float* part   = ws;
    float* qn     = ws + 4096;
    short* pqt    = (short*)(qn + 2097152);
    short* pkt    = pqt + 2097152;
    short* pvb    = pkt + 2097152;
    float* colmax = (float*)(pvb + 2097152);
    float* colinv = colmax + 32768;

    float* xout = (float*)d_out;            // (N, C*H*W)
    float* attn = xout + 2097152;           // (N, HW, HW)

    k_stats<<<dim3(8, 3, 32), 256, 0, stream>>>(q, k, v, part);
    k_proj<<<dim3(16, 32), 256, 0, stream>>>(q, k, v, w1, b1, w2, b2, w3, b3,
                                             wq, bq, wk, bk, wv, bv,
                                             part, qn, pqt, pkt, pvb);
    k_attnA<<<dim3(1024), dim3(512), 0, stream>>>(pqt, pkt, pvb, qn, xout,
                                                  colmax, colinv);
    k_attnW<<<dim3(2048), dim3(256), 0, stream>>>(pqt, pkt, colmax, colinv, attn);
}

// Round 10
// 89.126 us; speedup vs baseline: 5.5529x; 3.3307x over previous
//
#include <hip/hip_runtime.h>
#include <math.h>

#define NB   32
#define CCH  64
#define HWD  1024
#define CHW  65536     // C*H*W per sample
#define EPSV 1e-5f

typedef __attribute__((ext_vector_type(8))) short bf16x8;
typedef __attribute__((ext_vector_type(4))) float f32x4;

__device__ __forceinline__ unsigned f2b(float x) {
    union { float f; unsigned u; } v; v.f = x;
    return (v.u + 0x7fffu + ((v.u >> 16) & 1u)) >> 16;   // RNE bf16 bits
}
__device__ __forceinline__ float b2f(unsigned short u) {
    union { unsigned u; float f; } v; v.u = ((unsigned)u) << 16;
    return v.f;
}

// ---------------------------------------------------------------------------
// Kernel 1: partial LN stats. grid (chunk=8, which=3, n=32), block 256.
// ---------------------------------------------------------------------------
__global__ __launch_bounds__(256)
void k_stats(const float* __restrict__ q, const float* __restrict__ k,
             const float* __restrict__ v, float* __restrict__ part)
{
    const int chunk = blockIdx.x, which = blockIdx.y, n = blockIdx.z;
    const float* x = (which == 0) ? q : (which == 1 ? k : v);
    const float4* x4 = (const float4*)(x + (size_t)n * CHW) + chunk * 2048;
    float s = 0.f, ss = 0.f;
#pragma unroll
    for (int i = 0; i < 8; ++i) {
        float4 t = x4[threadIdx.x + i * 256];
        s  += t.x + t.y + t.z + t.w;
        ss += t.x * t.x + t.y * t.y + t.z * t.z + t.w * t.w;
    }
    __shared__ float rs[256], rss[256];
    rs[threadIdx.x] = s; rss[threadIdx.x] = ss;
    __syncthreads();
    for (int off = 128; off > 0; off >>= 1) {
        if (threadIdx.x < off) {
            rs[threadIdx.x]  += rs[threadIdx.x + off];
            rss[threadIdx.x] += rss[threadIdx.x + off];
        }
        __syncthreads();
    }
    if (threadIdx.x == 0) {
        const int b = (n * 3 + which) * 8 + chunk;
        part[b * 2 + 0] = rs[0];
        part[b * 2 + 1] = rss[0];
    }
}

// ---------------------------------------------------------------------------
// Kernel 2: finish stats + LayerNorm + 1x1-conv projections.
// grid (pt=16, n=32), block 256. LDS 35 KB -> 4 blocks/CU.
// ---------------------------------------------------------------------------
__global__ __launch_bounds__(256, 4)
void k_proj(const float* __restrict__ q,  const float* __restrict__ k,  const float* __restrict__ v,
            const float* __restrict__ w1, const float* __restrict__ b1,
            const float* __restrict__ w2, const float* __restrict__ b2,
            const float* __restrict__ w3, const float* __restrict__ b3,
            const float* __restrict__ wq, const float* __restrict__ bq,
            const float* __restrict__ wk, const float* __restrict__ bk,
            const float* __restrict__ wv, const float* __restrict__ bv,
            const float* __restrict__ part,
            float* __restrict__ qn, short* __restrict__ pqt,
            short* __restrict__ pkt, short* __restrict__ pvb)
{
    __shared__ float xn[64][68];
    __shared__ float wt[64][68];
    __shared__ float musd[6];
    const int pt = blockIdx.x, n = blockIdx.y;
    const int t = threadIdx.x;

    if (t < 3) {
        float s = 0.f, ss = 0.f;
#pragma unroll
        for (int cidx = 0; cidx < 8; ++cidx) {
            const int b = (n * 3 + t) * 8 + cidx;
            s  += part[b * 2 + 0];
            ss += part[b * 2 + 1];
        }
        const float mu = s * (1.0f / CHW);
        musd[t * 2 + 0] = mu;
        musd[t * 2 + 1] = rsqrtf(ss * (1.0f / CHW) - mu * mu + EPSV);
    }
    __syncthreads();

    const float* src[3]   = {q, k, v};
    const float* lw[3]    = {w1, w2, w3};
    const float* lb[3]    = {b1, b2, b3};
    const float* pw[3]    = {wq, wk, wv};
    const float* pbias[3] = {bq, bk, bv};
    const int p   = t & 63;
    const int ob  = (t >> 6) * 16;
    const int pix = pt * 64 + p;

    for (int tt = 0; tt < 3; ++tt) {
        for (int idx = t; idx < 4096; idx += 256) {
            const int o = idx >> 6, c = idx & 63;
            wt[c][o] = pw[tt][idx];
        }
        const float mu = musd[tt * 2], is = musd[tt * 2 + 1];
        for (int idx = t; idx < 1024; idx += 256) {
            const int c = idx >> 4, p4 = idx & 15;
            const int gi = c * HWD + pt * 64 + p4 * 4;
            float4 xv = *(const float4*)&src[tt][(size_t)n * CHW + gi];
            float4 w4 = *(const float4*)&lw[tt][gi];
            float4 b4 = *(const float4*)&lb[tt][gi];
            float4 r;
            r.x = (xv.x - mu) * is * w4.x + b4.x;
            r.y = (xv.y - mu) * is * w4.y + b4.y;
            r.z = (xv.z - mu) * is * w4.z + b4.z;
            r.w = (xv.w - mu) * is * w4.w + b4.w;
            *(float4*)&xn[c][p4 * 4] = r;
            if (tt == 0) *(float4*)&qn[(size_t)n * CHW + gi] = r;
        }
        __syncthreads();

        float acc[16];
#pragma unroll
        for (int i = 0; i < 16; ++i) acc[i] = pbias[tt][ob + i];
#pragma unroll 4
        for (int c = 0; c < 64; ++c) {
            const float xv = xn[c][p];
#pragma unroll
            for (int o4 = 0; o4 < 4; ++o4) {
                float4 w4 = *(const float4*)&wt[c][ob + o4 * 4];
                acc[o4 * 4 + 0] += w4.x * xv;
                acc[o4 * 4 + 1] += w4.y * xv;
                acc[o4 * 4 + 2] += w4.z * xv;
                acc[o4 * 4 + 3] += w4.w * xv;
            }
        }
        if (tt == 2) {          // V: [c][pix] bf16
#pragma unroll
            for (int i = 0; i < 16; ++i)
                pvb[(size_t)n * CHW + (ob + i) * HWD + pix] = (short)f2b(acc[i]);
        } else {                // Q^T / K^T: [pix][c] bf16 (Q pre-scaled 1/8)
            const float sc = (tt == 0) ? 0.125f : 1.0f;
            unsigned u[8];
#pragma unroll
            for (int i = 0; i < 8; ++i)
                u[i] = (f2b(acc[2 * i + 1] * sc) << 16) | f2b(acc[2 * i] * sc);
            short* dst = (tt == 0) ? pqt : pkt;
            *(uint4*)&dst[(size_t)n * CHW + pix * 64 + ob]     = *(uint4*)&u[0];
            *(uint4*)&dst[(size_t)n * CHW + pix * 64 + ob + 8] = *(uint4*)&u[4];
        }
        __syncthreads();
    }
}

// ---------------------------------------------------------------------------
// Kernel 3 (fused, role-split): one block per (n, 32-col tile), 8 waves.
// Phases 1-3 (all 8 waves): QK^T -> 1-barrier softmax (per-wave m_w,s_w +
// merged rescale exp(m_w-M)/S) -> normalized P (bf16) to swizzled LDS.
// Phase 4 SPLIT: waves 0-3 PV (unique c-tile each -> V read 1x) + xout;
// waves 4-7 write attn from P-LDS as FULL 128B rows (nontemporal), each
// owning a 256-i slab. Write stream overlaps PV MFMA stream.
// LDS 72 KB -> 2 blocks/CU.
// ---------------------------------------------------------------------------
__global__ __launch_bounds__(512, 4)
void k_attn3(const short* __restrict__ pqt, const short* __restrict__ pkt,
             const short* __restrict__ pvb, const float* __restrict__ qn,
             float* __restrict__ xout, float* __restrict__ attn)
{
    __shared__ __align__(16) char smem[65536 + 4608 + 2048];
    short* q_lds = (short*)(smem + 65536);
    float* wredM = (float*)(smem + 65536 + 4608);   // [8][32] per-wave max
    float* wredS = wredM + 256;                     // [8][32] per-wave sum

    // XCD-bijective swizzle: 1024 wgs = 8 XCDs x 128; 4 samples/XCD
    const int wg  = blockIdx.x;
    const int xcd = wg & 7, lid = wg >> 3;
    const int n   = xcd * 4 + (lid >> 5);
    const int jb  = lid & 31;
    const size_t nb = (size_t)n * CHW;
    const int t = threadIdx.x;
    const int w = t >> 6;
    const int l = t & 63;
    const int l15 = l & 15, lg = l >> 4;
    const int ibase = w * 128;

    // ---- stage Q^T tile: q_lds[j][c]
    if (t < 256) {
        const int j = t >> 3, c8 = (t & 7) * 8;
        *(bf16x8*)&q_lds[j * 72 + c8] =
            *(const bf16x8*)&pqt[nb + (size_t)(jb * 32 + j) * 64 + c8];
    }
    __syncthreads();

    // ---- phase 1: S = K^T Q  (acc[f][jt]: f = i-frag, jt = j-frag)
    f32x4 acc[8][2] = {};
#pragma unroll
    for (int ks = 0; ks < 2; ++ks) {
        bf16x8 bqf[2];
#pragma unroll
        for (int jt = 0; jt < 2; ++jt)
            bqf[jt] = *(const bf16x8*)&q_lds[(jt * 16 + l15) * 72 + ks * 32 + lg * 8];
#pragma unroll
        for (int f = 0; f < 8; ++f) {
            const int i = ibase + f * 16 + l15;
            bf16x8 af = *(const bf16x8*)&pkt[nb + (size_t)i * 64 + ks * 32 + lg * 8];
#pragma unroll
            for (int jt = 0; jt < 2; ++jt)
                acc[f][jt] = __builtin_amdgcn_mfma_f32_16x16x32_bf16(
                    af, bqf[jt], acc[f][jt], 0, 0, 0);
        }
    }

    // ---- phase 2: per-wave softmax (local max + exp + local sum), 1 barrier
    float mself[2];
#pragma unroll
    for (int jt = 0; jt < 2; ++jt) {
        float m = -1e30f;
#pragma unroll
        for (int f = 0; f < 8; ++f)
#pragma unroll
            for (int r = 0; r < 4; ++r) m = fmaxf(m, acc[f][jt][r]);
        m = fmaxf(m, __shfl_xor(m, 16));
        m = fmaxf(m, __shfl_xor(m, 32));
        mself[jt] = m;
        float s = 0.f;
#pragma unroll
        for (int f = 0; f < 8; ++f)
#pragma unroll
            for (int r = 0; r < 4; ++r) {
                float e = __expf(acc[f][jt][r] - m);
                acc[f][jt][r] = e;
                s += e;
            }
        s += __shfl_xor(s, 16);
        s += __shfl_xor(s, 32);
        if (l < 16) {
            wredM[w * 32 + jt * 16 + l] = m;
            wredS[w * 32 + jt * 16 + l] = s;
        }
    }
    __syncthreads();

    // ---- phase 3: merge across waves; normalize; P (bf16) -> swizzled LDS
#pragma unroll
    for (int jt = 0; jt < 2; ++jt) {
        const int j = jt * 16 + l15;
        float M = wredM[j];
#pragma unroll
        for (int ww = 1; ww < 8; ++ww) M = fmaxf(M, wredM[ww * 32 + j]);
        float S = 0.f;
#pragma unroll
        for (int ww = 0; ww < 8; ++ww)
            S += wredS[ww * 32 + j] * __expf(wredM[ww * 32 + j] - M);
        const float fac = __expf(mself[jt] - M) / S;
#pragma unroll
        for (int f = 0; f < 8; ++f) {
            const int i0 = ibase + f * 16 + lg * 4;
            uint2 pw;
            pw.x = (f2b(acc[f][jt][1] * fac) << 16) | f2b(acc[f][jt][0] * fac);
            pw.y = (f2b(acc[f][jt][3] * fac) << 16) | f2b(acc[f][jt][2] * fac);
            const unsigned byte = (unsigned)j * 2048u + (((unsigned)i0 * 2u) ^ (((unsigned)j & 7u) << 4));
            *(uint2*)(smem + byte) = pw;
        }
    }
    __syncthreads();

    // ---- phase 4 (role split)
    if (w < 4) {
        // PV: wave w owns c-tile w (16 c) x BOTH j-tiles. V read 1x per block.
        f32x4 oacc[2] = {};
        __builtin_amdgcn_s_setprio(1);
#pragma unroll 4
        for (int ks = 0; ks < 32; ++ks) {
            bf16x8 av = *(const bf16x8*)&pvb[nb + (size_t)(w * 16 + l15) * HWD + ks * 32 + lg * 8];
            const unsigned ib = (unsigned)(ks * 32 + lg * 8) * 2u;
#pragma unroll
            for (int u = 0; u < 2; ++u) {
                const int j = u * 16 + l15;
                bf16x8 bp = *(const bf16x8*)(smem + (unsigned)j * 2048u + (ib ^ (((unsigned)j & 7u) << 4)));
                oacc[u] = __builtin_amdgcn_mfma_f32_16x16x32_bf16(av, bp, oacc[u], 0, 0, 0);
            }
        }
        __builtin_amdgcn_s_setprio(0);
        // epilogue: x = qn + out
#pragma unroll
        for (int u = 0; u < 2; ++u) {
            const int j = u * 16 + l15;
#pragma unroll
            for (int r = 0; r < 4; ++r) {
                const int c = w * 16 + lg * 4 + r;
                const size_t o = nb + (size_t)c * HWD + jb * 32 + j;
                xout[o] = oacc[u][r] + qn[o];
            }
        }
    } else {
        // attn writer: wave (w-4) owns i in [(w-4)*256, +256).
        // lane l: j-quad = (l&7)*4, i = i00 + g*8 + (l>>3); per wave-instr the
        // 64 lanes cover 8 rows x 128B = 8 full lines (nontemporal f32x4).
        float* aout = attn + (size_t)n * HWD * HWD + jb * 32;
        const int jq   = (l & 7) * 4;
        const int isub = l >> 3;
        const int i00  = (w - 4) * 256;
#pragma unroll 4
        for (int g = 0; g < 32; ++g) {
            const int i = i00 + g * 8 + isub;
            f32x4 o4;
#pragma unroll
            for (int r = 0; r < 4; ++r) {
                const unsigned j = (unsigned)(jq + r);
                const unsigned byte = j * 2048u + (((unsigned)i * 2u) ^ ((j & 7u) << 4));
                o4[r] = b2f(*(const unsigned short*)(smem + byte));
            }
            __builtin_nontemporal_store(o4, (f32x4*)&aout[(size_t)i * HWD + jq]);
        }
    }
}

// ---------------------------------------------------------------------------
extern "C" void kernel_launch(void* const* d_in, const int* in_sizes, int n_in,
                              void* d_out, int out_size, void* d_ws, size_t ws_size,
                              hipStream_t stream)
{
    const float* q  = (const float*)d_in[0];
    const float* k  = (const float*)d_in[1];
    const float* v  = (const float*)d_in[2];
    const float* w1 = (const float*)d_in[3];
    const float* b1 = (const float*)d_in[4];
    const float* w2 = (const float*)d_in[5];
    const float* b2 = (const float*)d_in[6];
    const float* w3 = (const float*)d_in[7];
    const float* b3 = (const float*)d_in[8];
    const float* wq = (const float*)d_in[9];
    const float* bq = (const float*)d_in[10];
    const float* wk = (const float*)d_in[11];
    const float* bk = (const float*)d_in[12];
    const float* wv = (const float*)d_in[13];
    const float* bv = (const float*)d_in[14];

    // ws layout: part fp32 [1536] @0; qn fp32 @4096; pqt/pkt/pvb bf16 after.
    float* ws   = (float*)d_ws;
    float* part = ws;
    float* qn   = ws + 4096;
    short* pqt  = (short*)(qn + 2097152);
    short* pkt  = pqt + 2097152;
    short* pvb  = pkt + 2097152;

    float* xout = (float*)d_out;            // (N, C*H*W)
    float* attn = xout + 2097152;           // (N, HW, HW)

    k_stats<<<dim3(8, 3, 32), 256, 0, stream>>>(q, k, v, part);
    k_proj<<<dim3(16, 32), 256, 0, stream>>>(q, k, v, w1, b1, w2, b2, w3, b3,
                                             wq, bq, wk, bk, wv, bv,
                                             part, qn, pqt, pkt, pvb);
    k_attn3<<<dim3(1024), dim3(512), 0, stream>>>(pqt, pkt, pvb, qn, xout, attn);
}

// Round 11
// 74.026 us; speedup vs baseline: 6.6857x; 1.2040x over previous
//
#include <hip/hip_runtime.h>
#include <math.h>

#define NB   32
#define CCH  64
#define HWD  1024
#define CHW  65536     // C*H*W per sample
#define EPSV 1e-5f

typedef __attribute__((ext_vector_type(8))) short bf16x8;
typedef __attribute__((ext_vector_type(4))) float f32x4;

__device__ __forceinline__ unsigned f2b(float x) {
    union { float f; unsigned u; } v; v.f = x;
    return (v.u + 0x7fffu + ((v.u >> 16) & 1u)) >> 16;   // RNE bf16 bits
}
__device__ __forceinline__ float b2f(unsigned short u) {
    union { unsigned u; float f; } v; v.u = ((unsigned)u) << 16;
    return v.f;
}

// ---------------------------------------------------------------------------
// Kernel 1: partial LN stats. grid (chunk=8, which=3, n=32), block 256.
// ---------------------------------------------------------------------------
__global__ __launch_bounds__(256)
void k_stats(const float* __restrict__ q, const float* __restrict__ k,
             const float* __restrict__ v, float* __restrict__ part)
{
    const int chunk = blockIdx.x, which = blockIdx.y, n = blockIdx.z;
    const float* x = (which == 0) ? q : (which == 1 ? k : v);
    const float4* x4 = (const float4*)(x + (size_t)n * CHW) + chunk * 2048;
    float s = 0.f, ss = 0.f;
#pragma unroll
    for (int i = 0; i < 8; ++i) {
        float4 t = x4[threadIdx.x + i * 256];
        s  += t.x + t.y + t.z + t.w;
        ss += t.x * t.x + t.y * t.y + t.z * t.z + t.w * t.w;
    }
    __shared__ float rs[256], rss[256];
    rs[threadIdx.x] = s; rss[threadIdx.x] = ss;
    __syncthreads();
    for (int off = 128; off > 0; off >>= 1) {
        if (threadIdx.x < off) {
            rs[threadIdx.x]  += rs[threadIdx.x + off];
            rss[threadIdx.x] += rss[threadIdx.x + off];
        }
        __syncthreads();
    }
    if (threadIdx.x == 0) {
        const int b = (n * 3 + which) * 8 + chunk;
        part[b * 2 + 0] = rs[0];
        part[b * 2 + 1] = rss[0];
    }
}

// ---------------------------------------------------------------------------
// Kernel 2 (MFMA): LN + 1x1-conv projections. grid (pt=16, n=32), block 256.
// VALU matmul (measured ~24us, FMA-issue-bound: 64c x 16 FMA x 2cyc x 3tt)
// replaced by MFMA: xn staged bf16 [px][72c] in LDS; W loaded fp32 and split
// hi/lo bf16 (2 MFMAs) for near-fp32 weights. Q scale 1/8 folded into W,b.
// qn residual stays exact fp32 (unchanged vs R10). LDS 9.5 KB.
// ---------------------------------------------------------------------------
__global__ __launch_bounds__(256, 4)
void k_proj(const float* __restrict__ q,  const float* __restrict__ k,  const float* __restrict__ v,
            const float* __restrict__ w1, const float* __restrict__ b1,
            const float* __restrict__ w2, const float* __restrict__ b2,
            const float* __restrict__ w3, const float* __restrict__ b3,
            const float* __restrict__ wq, const float* __restrict__ bq,
            const float* __restrict__ wk, const float* __restrict__ bk,
            const float* __restrict__ wv, const float* __restrict__ bv,
            const float* __restrict__ part,
            float* __restrict__ qn, short* __restrict__ pqt,
            short* __restrict__ pkt, short* __restrict__ pvb)
{
    __shared__ short xnb[64][72];      // bf16 LN output, [pixel][channel]
    __shared__ float musd[6];
    const int pt = blockIdx.x, n = blockIdx.y;
    const int t = threadIdx.x;
    const int w = t >> 6, l = t & 63;
    const int l15 = l & 15, lg = l >> 4;

    if (t < 3) {
        float s = 0.f, ss = 0.f;
#pragma unroll
        for (int cidx = 0; cidx < 8; ++cidx) {
            const int b = (n * 3 + t) * 8 + cidx;
            s  += part[b * 2 + 0];
            ss += part[b * 2 + 1];
        }
        const float mu = s * (1.0f / CHW);
        musd[t * 2 + 0] = mu;
        musd[t * 2 + 1] = rsqrtf(ss * (1.0f / CHW) - mu * mu + EPSV);
    }
    __syncthreads();

    const float* src[3]   = {q, k, v};
    const float* lw[3]    = {w1, w2, w3};
    const float* lb[3]    = {b1, b2, b3};
    const float* pw[3]    = {wq, wk, wv};
    const float* pbias[3] = {bq, bk, bv};

    for (int tt = 0; tt < 3; ++tt) {
        const float sc = (tt == 0) ? 0.125f : 1.0f;     // fold 1/sqrt(C) into W,b

        // ---- W fragments: lane = (row l15, k lg*8+e); fp32 -> hi/lo bf16
        bf16x8 whi[2], wlo[2];
#pragma unroll
        for (int ks = 0; ks < 2; ++ks) {
            float wf[8];
            *(float4*)&wf[0] = *(const float4*)&pw[tt][(w * 16 + l15) * 64 + ks * 32 + lg * 8];
            *(float4*)&wf[4] = *(const float4*)&pw[tt][(w * 16 + l15) * 64 + ks * 32 + lg * 8 + 4];
#pragma unroll
            for (int e = 0; e < 8; ++e) {
                const float ws = wf[e] * sc;
                const unsigned hi = f2b(ws);
                whi[ks][e] = (short)hi;
                wlo[ks][e] = (short)f2b(ws - b2f((unsigned short)hi));
            }
        }

        // ---- stage: LN -> bf16 LDS (and exact fp32 qn for tt==0)
        const float mu = musd[tt * 2], is = musd[tt * 2 + 1];
        for (int idx = t; idx < 1024; idx += 256) {
            const int c = idx >> 4, p4 = idx & 15;
            const int gi = c * HWD + pt * 64 + p4 * 4;
            float4 xv = *(const float4*)&src[tt][(size_t)n * CHW + gi];
            float4 w4 = *(const float4*)&lw[tt][gi];
            float4 b4 = *(const float4*)&lb[tt][gi];
            float4 r;
            r.x = (xv.x - mu) * is * w4.x + b4.x;
            r.y = (xv.y - mu) * is * w4.y + b4.y;
            r.z = (xv.z - mu) * is * w4.z + b4.z;
            r.w = (xv.w - mu) * is * w4.w + b4.w;
            if (tt == 0) *(float4*)&qn[(size_t)n * CHW + gi] = r;
            xnb[p4 * 4 + 0][c] = (short)f2b(r.x);
            xnb[p4 * 4 + 1][c] = (short)f2b(r.y);
            xnb[p4 * 4 + 2][c] = (short)f2b(r.z);
            xnb[p4 * 4 + 3][c] = (short)f2b(r.w);
        }
        __syncthreads();

        // ---- MFMA: wave w owns o-tile w (16 o) x 4 px-tiles
        if (tt < 2) {
            // A=W(row=o), B=xn(col=px); D: o = w*16+lg*4+r, px = pt4*16+l15
            const float4 bb = *(const float4*)&pbias[tt][w * 16 + lg * 4];
            short* dst = (tt == 0) ? pqt : pkt;
#pragma unroll
            for (int pt4 = 0; pt4 < 4; ++pt4) {
                f32x4 acc = {};
#pragma unroll
                for (int ks = 0; ks < 2; ++ks) {
                    bf16x8 xb = *(const bf16x8*)&xnb[pt4 * 16 + l15][ks * 32 + lg * 8];
                    acc = __builtin_amdgcn_mfma_f32_16x16x32_bf16(whi[ks], xb, acc, 0, 0, 0);
                    acc = __builtin_amdgcn_mfma_f32_16x16x32_bf16(wlo[ks], xb, acc, 0, 0, 0);
                }
                const int pix = pt * 64 + pt4 * 16 + l15;
                uint2 u;
                u.x = (f2b(acc[1] + bb.y * sc) << 16) | f2b(acc[0] + bb.x * sc);
                u.y = (f2b(acc[3] + bb.w * sc) << 16) | f2b(acc[2] + bb.z * sc);
                *(uint2*)&dst[(size_t)n * CHW + pix * 64 + w * 16 + lg * 4] = u;
            }
        } else {
            // V: swap operands. A=xn(row=px), B=W(col=o); D: px=lg*4+r, o=l15
            const float bo = pbias[2][w * 16 + l15];
#pragma unroll
            for (int pt4 = 0; pt4 < 4; ++pt4) {
                f32x4 acc = {};
#pragma unroll
                for (int ks = 0; ks < 2; ++ks) {
                    bf16x8 xb = *(const bf16x8*)&xnb[pt4 * 16 + l15][ks * 32 + lg * 8];
                    acc = __builtin_amdgcn_mfma_f32_16x16x32_bf16(xb, whi[ks], acc, 0, 0, 0);
                    acc = __builtin_amdgcn_mfma_f32_16x16x32_bf16(xb, wlo[ks], acc, 0, 0, 0);
                }
                const int o   = w * 16 + l15;
                const int px4 = pt * 64 + pt4 * 16 + lg * 4;
                uint2 u;
                u.x = (f2b(acc[1] + bo) << 16) | f2b(acc[0] + bo);
                u.y = (f2b(acc[3] + bo) << 16) | f2b(acc[2] + bo);
                *(uint2*)&pvb[(size_t)n * CHW + o * HWD + px4] = u;
            }
        }
        __syncthreads();        // protect xnb before next tt overwrites
    }
}

// ---------------------------------------------------------------------------
// Kernel 3 (fused, role-split): one block per (n, 32-col tile), 8 waves.
// Identical to R10 (passing, 89us total). Phases 1-3 all waves; phase 4:
// waves 0-3 PV + xout, waves 4-7 stream attn from P-LDS (nontemporal lines).
// ---------------------------------------------------------------------------
__global__ __launch_bounds__(512, 4)
void k_attn3(const short* __restrict__ pqt, const short* __restrict__ pkt,
             const short* __restrict__ pvb, const float* __restrict__ qn,
             float* __restrict__ xout, float* __restrict__ attn)
{
    __shared__ __align__(16) char smem[65536 + 4608 + 2048];
    short* q_lds = (short*)(smem + 65536);
    float* wredM = (float*)(smem + 65536 + 4608);   // [8][32] per-wave max
    float* wredS = wredM + 256;                     // [8][32] per-wave sum

    const int wg  = blockIdx.x;
    const int xcd = wg & 7, lid = wg >> 3;
    const int n   = xcd * 4 + (lid >> 5);
    const int jb  = lid & 31;
    const size_t nb = (size_t)n * CHW;
    const int t = threadIdx.x;
    const int w = t >> 6;
    const int l = t & 63;
    const int l15 = l & 15, lg = l >> 4;
    const int ibase = w * 128;

    if (t < 256) {
        const int j = t >> 3, c8 = (t & 7) * 8;
        *(bf16x8*)&q_lds[j * 72 + c8] =
            *(const bf16x8*)&pqt[nb + (size_t)(jb * 32 + j) * 64 + c8];
    }
    __syncthreads();

    // ---- phase 1: S = K^T Q
    f32x4 acc[8][2] = {};
#pragma unroll
    for (int ks = 0; ks < 2; ++ks) {
        bf16x8 bqf[2];
#pragma unroll
        for (int jt = 0; jt < 2; ++jt)
            bqf[jt] = *(const bf16x8*)&q_lds[(jt * 16 + l15) * 72 + ks * 32 + lg * 8];
#pragma unroll
        for (int f = 0; f < 8; ++f) {
            const int i = ibase + f * 16 + l15;
            bf16x8 af = *(const bf16x8*)&pkt[nb + (size_t)i * 64 + ks * 32 + lg * 8];
#pragma unroll
            for (int jt = 0; jt < 2; ++jt)
                acc[f][jt] = __builtin_amdgcn_mfma_f32_16x16x32_bf16(
                    af, bqf[jt], acc[f][jt], 0, 0, 0);
        }
    }

    // ---- phase 2: per-wave softmax (local max + exp + local sum), 1 barrier
    float mself[2];
#pragma unroll
    for (int jt = 0; jt < 2; ++jt) {
        float m = -1e30f;
#pragma unroll
        for (int f = 0; f < 8; ++f)
#pragma unroll
            for (int r = 0; r < 4; ++r) m = fmaxf(m, acc[f][jt][r]);
        m = fmaxf(m, __shfl_xor(m, 16));
        m = fmaxf(m, __shfl_xor(m, 32));
        mself[jt] = m;
        float s = 0.f;
#pragma unroll
        for (int f = 0; f < 8; ++f)
#pragma unroll
            for (int r = 0; r < 4; ++r) {
                float e = __expf(acc[f][jt][r] - m);
                acc[f][jt][r] = e;
                s += e;
            }
        s += __shfl_xor(s, 16);
        s += __shfl_xor(s, 32);
        if (l < 16) {
            wredM[w * 32 + jt * 16 + l] = m;
            wredS[w * 32 + jt * 16 + l] = s;
        }
    }
    __syncthreads();

    // ---- phase 3: merge across waves; normalize; P (bf16) -> swizzled LDS
#pragma unroll
    for (int jt = 0; jt < 2; ++jt) {
        const int j = jt * 16 + l15;
        float M = wredM[j];
#pragma unroll
        for (int ww = 1; ww < 8; ++ww) M = fmaxf(M, wredM[ww * 32 + j]);
        float S = 0.f;
#pragma unroll
        for (int ww = 0; ww < 8; ++ww)
            S += wredS[ww * 32 + j] * __expf(wredM[ww * 32 + j] - M);
        const float fac = __expf(mself[jt] - M) / S;
#pragma unroll
        for (int f = 0; f < 8; ++f) {
            const int i0 = ibase + f * 16 + lg * 4;
            uint2 pw;
            pw.x = (f2b(acc[f][jt][1] * fac) << 16) | f2b(acc[f][jt][0] * fac);
            pw.y = (f2b(acc[f][jt][3] * fac) << 16) | f2b(acc[f][jt][2] * fac);
            const unsigned byte = (unsigned)j * 2048u + (((unsigned)i0 * 2u) ^ (((unsigned)j & 7u) << 4));
            *(uint2*)(smem + byte) = pw;
        }
    }
    __syncthreads();

    // ---- phase 4 (role split)
    if (w < 4) {
        f32x4 oacc[2] = {};
        __builtin_amdgcn_s_setprio(1);
#pragma unroll 4
        for (int ks = 0; ks < 32; ++ks) {
            bf16x8 av = *(const bf16x8*)&pvb[nb + (size_t)(w * 16 + l15) * HWD + ks * 32 + lg * 8];
            const unsigned ib = (unsigned)(ks * 32 + lg * 8) * 2u;
#pragma unroll
            for (int u = 0; u < 2; ++u) {
                const int j = u * 16 + l15;
                bf16x8 bp = *(const bf16x8*)(smem + (unsigned)j * 2048u + (ib ^ (((unsigned)j & 7u) << 4)));
                oacc[u] = __builtin_amdgcn_mfma_f32_16x16x32_bf16(av, bp, oacc[u], 0, 0, 0);
            }
        }
        __builtin_amdgcn_s_setprio(0);
#pragma unroll
        for (int u = 0; u < 2; ++u) {
            const int j = u * 16 + l15;
#pragma unroll
            for (int r = 0; r < 4; ++r) {
                const int c = w * 16 + lg * 4 + r;
                const size_t o = nb + (size_t)c * HWD + jb * 32 + j;
                xout[o] = oacc[u][r] + qn[o];
            }
        }
    } else {
        float* aout = attn + (size_t)n * HWD * HWD + jb * 32;
        const int jq   = (l & 7) * 4;
        const int isub = l >> 3;
        const int i00  = (w - 4) * 256;
#pragma unroll 4
        for (int g = 0; g < 32; ++g) {
            const int i = i00 + g * 8 + isub;
            f32x4 o4;
#pragma unroll
            for (int r = 0; r < 4; ++r) {
                const unsigned j = (unsigned)(jq + r);
                const unsigned byte = j * 2048u + (((unsigned)i * 2u) ^ ((j & 7u) << 4));
                o4[r] = b2f(*(const unsigned short*)(smem + byte));
            }
            __builtin_nontemporal_store(o4, (f32x4*)&aout[(size_t)i * HWD + jq]);
        }
    }
}

// ---------------------------------------------------------------------------
extern "C" void kernel_launch(void* const* d_in, const int* in_sizes, int n_in,
                              void* d_out, int out_size, void* d_ws, size_t ws_size,
                              hipStream_t stream)
{
    const float* q  = (const float*)d_in[0];
    const float* k  = (const float*)d_in[1];
    const float* v  = (const float*)d_in[2];
    const float* w1 = (const float*)d_in[3];
    const float* b1 = (const float*)d_in[4];
    const float* w2 = (const float*)d_in[5];
    const float* b2 = (const float*)d_in[6];
    const float* w3 = (const float*)d_in[7];
    const float* b3 = (const float*)d_in[8];
    const float* wq = (const float*)d_in[9];
    const float* bq = (const float*)d_in[10];
    const float* wk = (const float*)d_in[11];
    const float* bk = (const float*)d_in[12];
    const float* wv = (const float*)d_in[13];
    const float* bv = (const float*)d_in[14];

    // ws layout: part fp32 [1536] @0; qn fp32 @4096; pqt/pkt/pvb bf16 after.
    float* ws   = (float*)d_ws;
    float* part = ws;
    float* qn   = ws + 4096;
    short* pqt  = (short*)(qn + 2097152);
    short* pkt  = pqt + 2097152;
    short* pvb  = pkt + 2097152;

    float* xout = (float*)d_out;            // (N, C*H*W)
    float* attn = xout + 2097152;           // (N, HW, HW)

    k_stats<<<dim3(8, 3, 32), 256, 0, stream>>>(q, k, v, part);
    k_proj<<<dim3(16, 32), 256, 0, stream>>>(q, k, v, w1, b1, w2, b2, w3, b3,
                                             wq, bq, wk, bk, wv, bv,
                                             part, qn, pqt, pkt, pvb);
    k_attn3<<<dim3(1024), dim3(512), 0, stream>>>(pqt, pkt, pvb, qn, xout, attn);
}